// Round 7
// baseline (43.296 us; speedup 1.0000x reference)
//
#include <hip/hip_runtime.h>
#include <math.h>

// Health_State_Analysis: B=16384 rows, S=2560 fp32 -> 15 stats/row.
// Single kernel, 2 waves/row (half-row each, X[5]=20 regs/lane), coalesced
// interleave, DPP reductions, packed f32 pass-1, lag-correlation Hjorth,
// exact-f32-boundary outlier count. Cross-wave combine + inline f64 finalize
// via small LDS struct (no second kernel, no ws traffic).

typedef float f32x2 __attribute__((ext_vector_type(2)));
typedef float f32x4 __attribute__((ext_vector_type(4)));

constexpr int S_LEN = 2560;

#define DPP_ADD_F32(x, ctrl) do { \
    int t_ = __builtin_amdgcn_update_dpp(0, __float_as_int(x), ctrl, 0xf, 0xf, false); \
    x += __int_as_float(t_); } while (0)
#define DPP_MAX_F32(x, ctrl) do { \
    int t_ = __builtin_amdgcn_update_dpp(__float_as_int(x), __float_as_int(x), ctrl, 0xf, 0xf, false); \
    x = fmaxf(x, __int_as_float(t_)); } while (0)
#define DPP_MIN_F32(x, ctrl) do { \
    int t_ = __builtin_amdgcn_update_dpp(__float_as_int(x), __float_as_int(x), ctrl, 0xf, 0xf, false); \
    x = fminf(x, __int_as_float(t_)); } while (0)

__device__ __forceinline__ float wave_sum_f32(float x) {
    DPP_ADD_F32(x, 0x111); DPP_ADD_F32(x, 0x112); DPP_ADD_F32(x, 0x114);
    DPP_ADD_F32(x, 0x118); DPP_ADD_F32(x, 0x142); DPP_ADD_F32(x, 0x143);
    return x;  // total in lane 63
}
__device__ __forceinline__ float wave_max_f32(float x) {
    DPP_MAX_F32(x, 0x111); DPP_MAX_F32(x, 0x112); DPP_MAX_F32(x, 0x114);
    DPP_MAX_F32(x, 0x118); DPP_MAX_F32(x, 0x142); DPP_MAX_F32(x, 0x143);
    return x;
}
__device__ __forceinline__ float wave_min_f32(float x) {
    DPP_MIN_F32(x, 0x111); DPP_MIN_F32(x, 0x112); DPP_MIN_F32(x, 0x114);
    DPP_MIN_F32(x, 0x118); DPP_MIN_F32(x, 0x142); DPP_MIN_F32(x, 0x143);
    return x;
}
__device__ __forceinline__ double wave_sum_f64(double x) {
#define DPP_ADD_F64(ctrl) do { \
    long long b_ = __double_as_longlong(x); \
    int lo_ = __builtin_amdgcn_update_dpp(0, (int)(b_ & 0xffffffffLL), ctrl, 0xf, 0xf, false); \
    int hi_ = __builtin_amdgcn_update_dpp(0, (int)(b_ >> 32), ctrl, 0xf, 0xf, false); \
    x += __longlong_as_double(((long long)hi_ << 32) | (unsigned int)lo_); } while (0)
    DPP_ADD_F64(0x111); DPP_ADD_F64(0x112); DPP_ADD_F64(0x114);
    DPP_ADD_F64(0x118); DPP_ADD_F64(0x142); DPP_ADD_F64(0x143);
#undef DPP_ADD_F64
    return x;  // total in lane 63
}
__device__ __forceinline__ double readlane_f64(double x, int l) {
    long long b = __double_as_longlong(x);
    int lo = __builtin_amdgcn_readlane((int)(b & 0xffffffffLL), l);
    int hi = __builtin_amdgcn_readlane((int)(b >> 32), l);
    return __longlong_as_double(((long long)hi << 32) | (unsigned int)lo);
}

struct RowShared {
    double sum[2], sq[2];    // per half
    float  nb0, nb1;         // x[1280], x[1281] (half1 lane0's first two)
    // half1's reduced stats: sabs,vmax,vmin,c3,c4,r1,r2,outc,zcc,ep2,ep3
    float  h1v[11];
};

__global__ __launch_bounds__(256, 6)
void health_stats(const float* __restrict__ in, float* __restrict__ out) {
    __shared__ RowShared RS[2];

    const int lane = threadIdx.x & 63;
    const int wid  = threadIdx.x >> 6;   // 0..3
    const int hidx = wid & 1;            // half of row
    const int rsl  = wid >> 1;           // row slot in block
    const int row  = blockIdx.x * 2 + rsl;
    RowShared& R = RS[rsl];

    const f32x4* rp = reinterpret_cast<const f32x4*>(in)
                    + (size_t)row * (S_LEN / 4) + hidx * (1280 / 4) + lane;

    // ---- pass 1: coalesced load + packed raw sums ----
    f32x4 X[5];
#pragma unroll
    for (int k = 0; k < 5; ++k) X[k] = rp[k * 64];

    f32x2 sp = {0.f, 0.f}, qp = {0.f, 0.f}, sabsp = {0.f, 0.f};
    f32x2 vmaxp = {-INFINITY, -INFINITY}, vminp = {INFINITY, INFINITY};
#pragma unroll
    for (int k = 0; k < 5; ++k) {
        f32x2 lo = __builtin_shufflevector(X[k], X[k], 0, 1);
        f32x2 hi = __builtin_shufflevector(X[k], X[k], 2, 3);
        sp += lo + hi;
        qp = __builtin_elementwise_fma(lo, lo, qp);
        qp = __builtin_elementwise_fma(hi, hi, qp);
        sabsp += __builtin_elementwise_max(lo, -lo);
        sabsp += __builtin_elementwise_max(hi, -hi);
        vmaxp = __builtin_elementwise_max(vmaxp, __builtin_elementwise_max(lo, hi));
        vminp = __builtin_elementwise_min(vminp, __builtin_elementwise_min(lo, hi));
    }

    const double sum_l = (double)sp.x + (double)sp.y;
    const double sq_l  = (double)qp.x + (double)qp.y;
    const double sum_u = readlane_f64(wave_sum_f64(sum_l), 63);
    const double sq_u  = readlane_f64(wave_sum_f64(sq_l), 63);

    float sabs_t = wave_sum_f32(sabsp.x + sabsp.y);
    float vmax_t = wave_max_f32(fmaxf(vmaxp.x, vmaxp.y));
    float vmin_t = wave_min_f32(fminf(vminp.x, vminp.y));

    // exchange f64 sums with partner wave; half1 publishes x[1280],x[1281]
    if (lane == 0) {
        R.sum[hidx] = sum_u;  R.sq[hidx] = sq_u;
        if (hidx == 1) { R.nb0 = X[0][0]; R.nb1 = X[0][1]; }
    }
    __syncthreads();
    const double tsum = R.sum[0] + R.sum[1];
    const double tsq  = R.sq[0]  + R.sq[1];

    const double mean = tsum * (1.0 / S_LEN);
    const double var  = (tsq - tsum * mean) * (1.0 / (S_LEN - 1));  // n*mean^2 ~1 << tsq: no cancellation
    const double thr  = 3.0 * sqrt(var);

    // exact f32 decision boundaries: (x > bhi_f64) <=> (x > RD_f32(bhi)), bhi>0;
    // (x < blo_f64) <=> (x < RU_f32(blo)), blo<0. One bits-step toward 0 each.
    const double bhi = mean + thr, blo = mean - thr;
    float bhi_f = (float)bhi;
    if ((double)bhi_f > bhi) bhi_f = __int_as_float(__float_as_int(bhi_f) - 1);
    float blo_f = (float)blo;
    if ((double)blo_f < blo) blo_f = __int_as_float(__float_as_int(blo_f) - 1);

    // half0 tail splices x[1280],x[1281]; half1 tail -> 0 (zeroes invalid lag products)
    const float nbv0 = (hidx == 0) ? R.nb0 : 0.f;
    const float nbv1 = (hidx == 0) ? R.nb1 : 0.f;
    const float mf = (float)mean;
    const f32x2 nmf2 = {-mf, -mf};
    const int nli = (lane + 1) & 63;
    const unsigned long long tail_ok = (hidx == 0) ? ~0ULL : 0x7FFFFFFFFFFFFFFFULL;

    // ---- pass 2: packed moments, outliers, zcr, lag correlations ----
    f32x2 c3p = {0.f, 0.f}, c4p = {0.f, 0.f};
    float r1 = 0.f, r2 = 0.f;
    int outc = 0, zcc = 0;

#pragma unroll
    for (int k = 0; k < 5; ++k) {
        const float x0 = X[k][0], x1 = X[k][1], x2v = X[k][2], x3 = X[k][3];
        const int kn = (k == 4) ? 0 : (k + 1);
        float v0 = (lane == 0) ? X[kn][0] : x0;
        float v1 = (lane == 0) ? X[kn][1] : x1;
        float n0 = __shfl(v0, nli);
        float n1 = __shfl(v1, nli);
        if (k == 4 && lane == 63) { n0 = nbv0; n1 = nbv1; }

        f32x2 lo = __builtin_shufflevector(X[k], X[k], 0, 1);
        f32x2 hi = __builtin_shufflevector(X[k], X[k], 2, 3);
        f32x2 cl = lo + nmf2, ch = hi + nmf2;
        f32x2 ql = cl * cl,  qh = ch * ch;
        c3p = __builtin_elementwise_fma(ql, cl, c3p);
        c3p = __builtin_elementwise_fma(qh, ch, c3p);
        c4p = __builtin_elementwise_fma(ql, ql, c4p);
        c4p = __builtin_elementwise_fma(qh, qh, c4p);

        outc += __popcll(__ballot(x0  > bhi_f || x0  < blo_f));
        outc += __popcll(__ballot(x1  > bhi_f || x1  < blo_f));
        outc += __popcll(__ballot(x2v > bhi_f || x2v < blo_f));
        outc += __popcll(__ballot(x3  > bhi_f || x3  < blo_f));

        const unsigned long long m0 = __ballot(x0  < 0.f);
        const unsigned long long m1 = __ballot(x1  < 0.f);
        const unsigned long long m2 = __ballot(x2v < 0.f);
        const unsigned long long m3 = __ballot(x3  < 0.f);
        const unsigned long long mn = __ballot(n0  < 0.f);
        zcc += __popcll(m0 ^ m1) + __popcll(m1 ^ m2) + __popcll(m2 ^ m3);
        zcc += __popcll((m3 ^ mn) & ((k == 4) ? tail_ok : ~0ULL));

        r1 = fmaf(x0, x1, fmaf(x1, x2v, fmaf(x2v, x3, fmaf(x3, n0, r1))));
        r2 = fmaf(x0, x2v, fmaf(x1, x3, fmaf(x2v, n0, fmaf(x3, n1, r2))));
    }

    const float c3_t = wave_sum_f32(c3p.x + c3p.y);
    const float c4_t = wave_sum_f32(c4p.x + c4p.y);
    const float r1_t = wave_sum_f32(r1);
    const float r2_t = wave_sum_f32(r2);

    // ---- half1 publishes its reduced stats; half0 lane 63 finalizes ----
    if (hidx == 1 && lane == 63) {
        R.h1v[0] = sabs_t; R.h1v[1] = vmax_t; R.h1v[2] = vmin_t;
        R.h1v[3] = c3_t;   R.h1v[4] = c4_t;
        R.h1v[5] = r1_t;   R.h1v[6] = r2_t;
        R.h1v[7] = (float)outc; R.h1v[8] = (float)zcc;
        R.h1v[9] = X[4][2]; R.h1v[10] = X[4][3];   // x[2558], x[2559]
    }
    // half0: row-head endpoints x[0], x[1] (wave-uniform via readlane)
    const float ep0 = __int_as_float(__builtin_amdgcn_readlane(__float_as_int(X[0][0]), 0));
    const float ep1 = __int_as_float(__builtin_amdgcn_readlane(__float_as_int(X[0][1]), 0));

    __syncthreads();

    if (hidx == 0 && lane == 63) {
        const float tabs = sabs_t + R.h1v[0];
        const float tmax = fmaxf(vmax_t, R.h1v[1]);
        const float tmin = fminf(vmin_t, R.h1v[2]);
        const float c3f  = c3_t + R.h1v[3];
        const float c4f  = c4_t + R.h1v[4];
        const double r1d = (double)r1_t + (double)R.h1v[5];
        const double r2d = (double)r2_t + (double)R.h1v[6];
        const float outt = (float)outc + R.h1v[7];
        const float zct  = (float)zcc + R.h1v[8];
        const double e2 = (double)R.h1v[9], e3 = (double)R.h1v[10];
        const double e0 = (double)ep0, e1 = (double)ep1;

        const double stdv = sqrt(var);
        const double rms  = sqrt(tsq * (1.0 / S_LEN));
        const double m3d  = (double)c3f * (1.0 / S_LEN);
        const double m4d  = (double)c4f * (1.0 / S_LEN);
        const double skew = m3d / (var * stdv);
        const double kurt = m4d / (var * var);
        const float  amax = fmaxf(fabsf(tmax), fabsf(tmin));
        const double shape   = rms * (double)S_LEN / (double)tabs;
        const double impulse = (double)amax * (double)S_LEN / (double)tabs;

        // Hjorth via lag-correlation identities (exact over the f32 samples):
        const double Q = tsq;
        const double s1q = 2.0 * Q - 2.0 * r1d - e0 * e0 - e3 * e3;
        const double s2q = 6.0 * Q - 8.0 * r1d + 2.0 * r2d
                         + 4.0 * (e0 * e1 + e2 * e3)
                         - 5.0 * e0 * e0 - e1 * e1 - e2 * e2 - 5.0 * e3 * e3;
        const double sd1 = e3 - e0;
        const double sd2 = (e3 - e2) - (e1 - e0);
        const double var1 = (s1q - sd1 * sd1 * (1.0 / (S_LEN - 1))) * (1.0 / (S_LEN - 2));
        const double var2 = (s2q - sd2 * sd2 * (1.0 / (S_LEN - 2))) * (1.0 / (S_LEN - 3));

        float* o = out + (size_t)row * 15;
        o[0]  = (float)mean;
        o[1]  = tmax;
        o[2]  = tmin;
        o[3]  = tmax - tmin;
        o[4]  = (float)var;
        o[5]  = (float)rms;
        o[6]  = (float)skew;
        o[7]  = (float)kurt;
        o[8]  = (float)shape;
        o[9]  = (float)impulse;
        o[10] = outt;
        o[11] = zct * (1.0f / (2.0f * S_LEN));
        o[12] = (float)var;
        o[13] = (float)sqrt(var1 / var);
        o[14] = (float)sqrt(var2 / var1);
    }
}

extern "C" void kernel_launch(void* const* d_in, const int* in_sizes, int n_in,
                              void* d_out, int out_size, void* d_ws, size_t ws_size,
                              hipStream_t stream) {
    (void)in_sizes; (void)n_in; (void)d_ws; (void)ws_size; (void)out_size;
    const float* in = (const float*)d_in[0];
    float* out = (float*)d_out;
    // 16384 rows, 2 rows per 256-thread block (2 waves per row), single kernel
    health_stats<<<8192, 256, 0, stream>>>(in, out);
}

// Round 8
// 42.548 us; speedup vs baseline: 1.0176x; 1.0176x over previous
//
#include <hip/hip_runtime.h>
#include <math.h>

// Health_State_Analysis: B=16384 rows, S=2560 fp32 -> 15 stats/row.
// R5 structure (best: 36.7us) with ONE change: k1 __launch_bounds__(256,8)
// (VGPR cap 64, 8 waves/SIMD) for more load-phase overlap.
// k1: 2 waves/row, coalesced interleave, DPP reductions, packed moments,
//     lag-correlation (r1,r2) replacing diff streams.
// k2: 16384 threads, f64 finalization incl. Hjorth algebra.

typedef float f32x2 __attribute__((ext_vector_type(2)));
typedef float f32x4 __attribute__((ext_vector_type(4)));

constexpr int S_LEN = 2560;
constexpr int NROWS = 16384;

#define DPP_ADD_F32(x, ctrl) do { \
    int t_ = __builtin_amdgcn_update_dpp(0, __float_as_int(x), ctrl, 0xf, 0xf, false); \
    x += __int_as_float(t_); } while (0)
#define DPP_MAX_F32(x, ctrl) do { \
    int t_ = __builtin_amdgcn_update_dpp(__float_as_int(x), __float_as_int(x), ctrl, 0xf, 0xf, false); \
    x = fmaxf(x, __int_as_float(t_)); } while (0)
#define DPP_MIN_F32(x, ctrl) do { \
    int t_ = __builtin_amdgcn_update_dpp(__float_as_int(x), __float_as_int(x), ctrl, 0xf, 0xf, false); \
    x = fminf(x, __int_as_float(t_)); } while (0)

__device__ __forceinline__ float wave_sum_f32(float x) {
    DPP_ADD_F32(x, 0x111); DPP_ADD_F32(x, 0x112); DPP_ADD_F32(x, 0x114);
    DPP_ADD_F32(x, 0x118); DPP_ADD_F32(x, 0x142); DPP_ADD_F32(x, 0x143);
    return x;  // total in lane 63
}
__device__ __forceinline__ float wave_max_f32(float x) {
    DPP_MAX_F32(x, 0x111); DPP_MAX_F32(x, 0x112); DPP_MAX_F32(x, 0x114);
    DPP_MAX_F32(x, 0x118); DPP_MAX_F32(x, 0x142); DPP_MAX_F32(x, 0x143);
    return x;
}
__device__ __forceinline__ float wave_min_f32(float x) {
    DPP_MIN_F32(x, 0x111); DPP_MIN_F32(x, 0x112); DPP_MIN_F32(x, 0x114);
    DPP_MIN_F32(x, 0x118); DPP_MIN_F32(x, 0x142); DPP_MIN_F32(x, 0x143);
    return x;
}
__device__ __forceinline__ double wave_sum_f64(double x) {
#define DPP_ADD_F64(ctrl) do { \
    long long b_ = __double_as_longlong(x); \
    int lo_ = __builtin_amdgcn_update_dpp(0, (int)(b_ & 0xffffffffLL), ctrl, 0xf, 0xf, false); \
    int hi_ = __builtin_amdgcn_update_dpp(0, (int)(b_ >> 32), ctrl, 0xf, 0xf, false); \
    x += __longlong_as_double(((long long)hi_ << 32) | (unsigned int)lo_); } while (0)
    DPP_ADD_F64(0x111); DPP_ADD_F64(0x112); DPP_ADD_F64(0x114);
    DPP_ADD_F64(0x118); DPP_ADD_F64(0x142); DPP_ADD_F64(0x143);
#undef DPP_ADD_F64
    return x;  // total in lane 63
}
__device__ __forceinline__ double readlane_f64(double x, int l) {
    long long b = __double_as_longlong(x);
    int lo = __builtin_amdgcn_readlane((int)(b & 0xffffffffLL), l);
    int hi = __builtin_amdgcn_readlane((int)(b >> 32), l);
    return __longlong_as_double(((long long)hi << 32) | (unsigned int)lo);
}

__global__ __launch_bounds__(256, 8)
void health_pass1(const float* __restrict__ in, float* __restrict__ ws) {
    __shared__ double Lsum[4], Lsq[4];
    __shared__ float  Lnb[2][2];

    const int lane = threadIdx.x & 63;
    const int wid  = threadIdx.x >> 6;   // 0..3
    const int hidx = wid & 1;            // half of row
    const int rsl  = wid >> 1;           // row slot in block
    const int row  = blockIdx.x * 2 + rsl;

    const f32x4* rp = reinterpret_cast<const f32x4*>(in)
                    + (size_t)row * (S_LEN / 4) + hidx * (1280 / 4) + lane;

    // ---- pass 1: coalesced load + raw sums (packed f32 -> f64 per lane) ----
    f32x4 X[5];
#pragma unroll
    for (int k = 0; k < 5; ++k) X[k] = rp[k * 64];

    f32x2 sp = {0.f, 0.f}, qp = {0.f, 0.f}, sabsp = {0.f, 0.f};
    f32x2 vmaxp = {-INFINITY, -INFINITY}, vminp = {INFINITY, INFINITY};
#pragma unroll
    for (int k = 0; k < 5; ++k) {
        f32x2 lo = __builtin_shufflevector(X[k], X[k], 0, 1);
        f32x2 hi = __builtin_shufflevector(X[k], X[k], 2, 3);
        sp += lo + hi;
        qp = __builtin_elementwise_fma(lo, lo, qp);
        qp = __builtin_elementwise_fma(hi, hi, qp);
        sabsp += __builtin_elementwise_max(lo, -lo);
        sabsp += __builtin_elementwise_max(hi, -hi);
        vmaxp = __builtin_elementwise_max(vmaxp, __builtin_elementwise_max(lo, hi));
        vminp = __builtin_elementwise_min(vminp, __builtin_elementwise_min(lo, hi));
    }

    const double sum_l = (double)sp.x + (double)sp.y;
    const double sq_l  = (double)qp.x + (double)qp.y;
    const double sum_u = readlane_f64(wave_sum_f64(sum_l), 63);
    const double sq_u  = readlane_f64(wave_sum_f64(sq_l), 63);

    float sabs = wave_sum_f32(sabsp.x + sabsp.y);
    float vmax = wave_max_f32(fmaxf(vmaxp.x, vmaxp.y));
    float vmin = wave_min_f32(fminf(vminp.x, vminp.y));

    // exchange sums with partner wave (other half of row)
    if (lane == 0) {
        Lsum[wid] = sum_u;  Lsq[wid] = sq_u;
        if (hidx == 1) { Lnb[rsl][0] = X[0][0]; Lnb[rsl][1] = X[0][1]; }
    }
    __syncthreads();
    const double tsum = Lsum[rsl * 2] + Lsum[rsl * 2 + 1];
    const double tsq  = Lsq[rsl * 2]  + Lsq[rsl * 2 + 1];

    const double mean = tsum * (1.0 / S_LEN);
    const double var  = (tsq - tsum * mean) * (1.0 / (S_LEN - 1));
    const double thr  = 3.0 * sqrt(var);
    const double bhi = mean + thr, blo = mean - thr;
    float bhi_f = (float)bhi;
    if ((double)bhi_f > bhi) bhi_f = __int_as_float(__float_as_int(bhi_f) - 1);  // RD (bhi>0)
    float blo_f = (float)blo;
    if ((double)blo_f < blo) blo_f = __int_as_float(__float_as_int(blo_f) - 1);  // RU (blo<0)

    // half0 tail splices x[1280],x[1281]; half1 tail pairs don't exist -> 0
    // (zero neighbor makes the invalid lag products vanish exactly)
    const float nbv0 = (hidx == 0) ? Lnb[rsl][0] : 0.f;
    const float nbv1 = (hidx == 0) ? Lnb[rsl][1] : 0.f;
    const float mf = (float)mean;
    const f32x2 nmf2 = {-mf, -mf};
    const unsigned long long tail_ok = (hidx == 0) ? ~0ULL : 0x7FFFFFFFFFFFFFFFULL;

    // ---- pass 2: moments (packed), outliers, zcr, lag correlations ----
    f32x2 c3p = {0.f, 0.f}, c4p = {0.f, 0.f};
    float r1 = 0.f, r2 = 0.f;
    int outc = 0, zcc = 0;
    const int nli = (lane + 1) & 63;

#pragma unroll
    for (int k = 0; k < 5; ++k) {
        const float x0 = X[k][0], x1 = X[k][1], x2v = X[k][2], x3 = X[k][3];
        const int kn = (k == 4) ? 0 : (k + 1);
        float v0 = (lane == 0) ? X[kn][0] : x0;
        float v1 = (lane == 0) ? X[kn][1] : x1;
        float n0 = __shfl(v0, nli);
        float n1 = __shfl(v1, nli);
        if (k == 4 && lane == 63) { n0 = nbv0; n1 = nbv1; }

        f32x2 lo = __builtin_shufflevector(X[k], X[k], 0, 1);
        f32x2 hi = __builtin_shufflevector(X[k], X[k], 2, 3);
        f32x2 cl = lo + nmf2, ch = hi + nmf2;
        f32x2 ql = cl * cl,  qh = ch * ch;
        c3p = __builtin_elementwise_fma(ql, cl, c3p);
        c3p = __builtin_elementwise_fma(qh, ch, c3p);
        c4p = __builtin_elementwise_fma(ql, ql, c4p);
        c4p = __builtin_elementwise_fma(qh, qh, c4p);

        outc += __popcll(__ballot(x0  > bhi_f || x0  < blo_f));
        outc += __popcll(__ballot(x1  > bhi_f || x1  < blo_f));
        outc += __popcll(__ballot(x2v > bhi_f || x2v < blo_f));
        outc += __popcll(__ballot(x3  > bhi_f || x3  < blo_f));

        const unsigned long long m0 = __ballot(x0  < 0.f);
        const unsigned long long m1 = __ballot(x1  < 0.f);
        const unsigned long long m2 = __ballot(x2v < 0.f);
        const unsigned long long m3 = __ballot(x3  < 0.f);
        const unsigned long long mn = __ballot(n0  < 0.f);
        zcc += __popcll(m0 ^ m1) + __popcll(m1 ^ m2) + __popcll(m2 ^ m3);
        zcc += __popcll((m3 ^ mn) & ((k == 4) ? tail_ok : ~0ULL));

        // lag-1 / lag-2 correlations (replace d1/d2 squared-diff streams)
        r1 = fmaf(x0, x1, fmaf(x1, x2v, fmaf(x2v, x3, fmaf(x3, n0, r1))));
        r2 = fmaf(x0, x2v, fmaf(x1, x3, fmaf(x2v, n0, fmaf(x3, n1, r2))));
    }

    float sabs_t = sabs;
    float c3_t   = wave_sum_f32(c3p.x + c3p.y);
    float c4_t   = wave_sum_f32(c4p.x + c4p.y);
    float r1_t   = wave_sum_f32(r1);
    float r2_t   = wave_sum_f32(r2);
    float vmax_t = vmax;
    float vmin_t = vmin;

    float ep_a, ep_b;   // half0: x[0],x[1];  half1: x[2558],x[2559]
    if (hidx == 0) {
        ep_a = __int_as_float(__builtin_amdgcn_readlane(__float_as_int(X[0][0]), 0));
        ep_b = __int_as_float(__builtin_amdgcn_readlane(__float_as_int(X[0][1]), 0));
    } else {
        ep_a = X[4][2];  ep_b = X[4][3];   // valid on lane 63 (the storing lane)
    }

    if (lane == 63) {
        double2* Wd = reinterpret_cast<double2*>(ws);
        f32x4*   Wf = reinterpret_cast<f32x4*>(ws);
        double2 dsum; dsum.x = sum_u; dsum.y = sq_u;
        Wd[(size_t)hidx * NROWS + row] = dsum;                       // chunks 0,1
        const size_t b = (size_t)(2 + hidx * 3) * NROWS + row;       // chunks 2..7
        Wf[b]             = f32x4{sabs_t, vmax_t, vmin_t, c3_t};
        Wf[b + NROWS]     = f32x4{c4_t, r1_t, r2_t, (float)outc};
        Wf[b + 2 * NROWS] = f32x4{(float)zcc, ep_a, ep_b, 0.f};
    }
}

__global__ __launch_bounds__(256)
void health_finalize(const float* __restrict__ ws, float* __restrict__ out) {
    const int row = blockIdx.x * 256 + threadIdx.x;
    const double2* Wd = reinterpret_cast<const double2*>(ws);
    const f32x4*   Wf = reinterpret_cast<const f32x4*>(ws);

    const double2 s0 = Wd[row], s1 = Wd[NROWS + row];
    const f32x4 a0 = Wf[2 * NROWS + row], a1 = Wf[3 * NROWS + row], a2 = Wf[4 * NROWS + row];
    const f32x4 b0 = Wf[5 * NROWS + row], b1 = Wf[6 * NROWS + row], b2 = Wf[7 * NROWS + row];

    const double tsum = s0.x + s1.x;
    const double tsq  = s0.y + s1.y;
    const double mean = tsum * (1.0 / S_LEN);
    const double var  = (tsq - tsum * mean) * (1.0 / (S_LEN - 1));
    const double stdv = sqrt(var);

    const float tabs = a0[0] + b0[0];
    const float tmax = fmaxf(a0[1], b0[1]);
    const float tmin = fminf(a0[2], b0[2]);
    const float c3t  = a0[3] + b0[3];
    const float c4t  = a1[0] + b1[0];
    const double r1t = (double)a1[1] + (double)b1[1];
    const double r2t = (double)a1[2] + (double)b1[2];
    const float outt = a1[3] + b1[3];
    const float zct  = a2[0] + b2[0];
    const double e0 = (double)a2[1], e1 = (double)a2[2];   // x[0], x[1]
    const double e2 = (double)b2[1], e3 = (double)b2[2];   // x[2558], x[2559]

    const double rms  = sqrt(tsq * (1.0 / S_LEN));
    const double m3   = (double)c3t * (1.0 / S_LEN);
    const double m4   = (double)c4t * (1.0 / S_LEN);
    const double skew = m3 / (var * stdv);
    const double kurt = m4 / (var * var);
    const float  amax = fmaxf(fabsf(tmax), fabsf(tmin));
    const double shape   = rms * (double)S_LEN / (double)tabs;
    const double impulse = (double)amax * (double)S_LEN / (double)tabs;

    // Hjorth via lag-correlation identities (exact over the f32 samples):
    const double Q = tsq;
    const double s1q = 2.0 * Q - 2.0 * r1t - e0 * e0 - e3 * e3;
    const double s2q = 6.0 * Q - 8.0 * r1t + 2.0 * r2t
                     + 4.0 * (e0 * e1 + e2 * e3)
                     - 5.0 * e0 * e0 - e1 * e1 - e2 * e2 - 5.0 * e3 * e3;
    const double sd1 = e3 - e0;
    const double sd2 = (e3 - e2) - (e1 - e0);
    const double var1 = (s1q - sd1 * sd1 * (1.0 / (S_LEN - 1))) * (1.0 / (S_LEN - 2));
    const double var2 = (s2q - sd2 * sd2 * (1.0 / (S_LEN - 2))) * (1.0 / (S_LEN - 3));

    float* o = out + (size_t)row * 15;
    o[0]  = (float)mean;
    o[1]  = tmax;
    o[2]  = tmin;
    o[3]  = tmax - tmin;
    o[4]  = (float)var;
    o[5]  = (float)rms;
    o[6]  = (float)skew;
    o[7]  = (float)kurt;
    o[8]  = (float)shape;
    o[9]  = (float)impulse;
    o[10] = outt;
    o[11] = zct * (1.0f / (2.0f * S_LEN));
    o[12] = (float)var;
    o[13] = (float)sqrt(var1 / var);
    o[14] = (float)sqrt(var2 / var1);
}

extern "C" void kernel_launch(void* const* d_in, const int* in_sizes, int n_in,
                              void* d_out, int out_size, void* d_ws, size_t ws_size,
                              hipStream_t stream) {
    (void)in_sizes; (void)n_in; (void)ws_size; (void)out_size;
    const float* in = (const float*)d_in[0];
    float* out = (float*)d_out;
    float* ws  = (float*)d_ws;
    health_pass1<<<8192, 256, 0, stream>>>(in, ws);
    health_finalize<<<64, 256, 0, stream>>>(ws, out);
}

// Round 9
// 38.920 us; speedup vs baseline: 1.1124x; 1.0932x over previous
//
#include <hip/hip_runtime.h>
#include <math.h>

// Health_State_Analysis: B=16384 rows, S=2560 fp32 -> 15 stats/row.
// R5 structure, (256,6), with pass rebalance: ALL streaming stats (raw moments
// Σx³/Σx⁴, zcr, lag r1/r2, abs/max/min, f64 Σx/Σx²) computed PRE-barrier;
// post-barrier tail = outlier ballots only (+ seam fixups + 2 reductions).
// Central moments recovered from raw moments in k2 (f64 binomial).

typedef float f32x2 __attribute__((ext_vector_type(2)));
typedef float f32x4 __attribute__((ext_vector_type(4)));

constexpr int S_LEN = 2560;
constexpr int NROWS = 16384;

#define DPP_ADD_F32(x, ctrl) do { \
    int t_ = __builtin_amdgcn_update_dpp(0, __float_as_int(x), ctrl, 0xf, 0xf, false); \
    x += __int_as_float(t_); } while (0)
#define DPP_MAX_F32(x, ctrl) do { \
    int t_ = __builtin_amdgcn_update_dpp(__float_as_int(x), __float_as_int(x), ctrl, 0xf, 0xf, false); \
    x = fmaxf(x, __int_as_float(t_)); } while (0)
#define DPP_MIN_F32(x, ctrl) do { \
    int t_ = __builtin_amdgcn_update_dpp(__float_as_int(x), __float_as_int(x), ctrl, 0xf, 0xf, false); \
    x = fminf(x, __int_as_float(t_)); } while (0)

__device__ __forceinline__ float wave_sum_f32(float x) {
    DPP_ADD_F32(x, 0x111); DPP_ADD_F32(x, 0x112); DPP_ADD_F32(x, 0x114);
    DPP_ADD_F32(x, 0x118); DPP_ADD_F32(x, 0x142); DPP_ADD_F32(x, 0x143);
    return x;  // total in lane 63
}
__device__ __forceinline__ float wave_max_f32(float x) {
    DPP_MAX_F32(x, 0x111); DPP_MAX_F32(x, 0x112); DPP_MAX_F32(x, 0x114);
    DPP_MAX_F32(x, 0x118); DPP_MAX_F32(x, 0x142); DPP_MAX_F32(x, 0x143);
    return x;
}
__device__ __forceinline__ float wave_min_f32(float x) {
    DPP_MIN_F32(x, 0x111); DPP_MIN_F32(x, 0x112); DPP_MIN_F32(x, 0x114);
    DPP_MIN_F32(x, 0x118); DPP_MIN_F32(x, 0x142); DPP_MIN_F32(x, 0x143);
    return x;
}
__device__ __forceinline__ double wave_sum_f64(double x) {
#define DPP_ADD_F64(ctrl) do { \
    long long b_ = __double_as_longlong(x); \
    int lo_ = __builtin_amdgcn_update_dpp(0, (int)(b_ & 0xffffffffLL), ctrl, 0xf, 0xf, false); \
    int hi_ = __builtin_amdgcn_update_dpp(0, (int)(b_ >> 32), ctrl, 0xf, 0xf, false); \
    x += __longlong_as_double(((long long)hi_ << 32) | (unsigned int)lo_); } while (0)
    DPP_ADD_F64(0x111); DPP_ADD_F64(0x112); DPP_ADD_F64(0x114);
    DPP_ADD_F64(0x118); DPP_ADD_F64(0x142); DPP_ADD_F64(0x143);
#undef DPP_ADD_F64
    return x;  // total in lane 63
}
__device__ __forceinline__ double readlane_f64(double x, int l) {
    long long b = __double_as_longlong(x);
    int lo = __builtin_amdgcn_readlane((int)(b & 0xffffffffLL), l);
    int hi = __builtin_amdgcn_readlane((int)(b >> 32), l);
    return __longlong_as_double(((long long)hi << 32) | (unsigned int)lo);
}

__global__ __launch_bounds__(256, 6)
void health_pass1(const float* __restrict__ in, float* __restrict__ ws) {
    __shared__ double Lsum[4], Lsq[4];
    __shared__ float  Lnb[2][2];

    const int lane = threadIdx.x & 63;
    const int wid  = threadIdx.x >> 6;   // 0..3
    const int hidx = wid & 1;            // half of row
    const int rsl  = wid >> 1;           // row slot in block
    const int row  = blockIdx.x * 2 + rsl;

    const f32x4* rp = reinterpret_cast<const f32x4*>(in)
                    + (size_t)row * (S_LEN / 4) + hidx * (1280 / 4) + lane;

    f32x4 X[5];
#pragma unroll
    for (int k = 0; k < 5; ++k) X[k] = rp[k * 64];

    // ---- pass 1 (pre-barrier): ALL mean-independent stats ----
    f32x2 sp = {0.f, 0.f}, qp = {0.f, 0.f}, sabsp = {0.f, 0.f};
    f32x2 c3p = {0.f, 0.f}, c4p = {0.f, 0.f};
    f32x2 vmaxp = {-INFINITY, -INFINITY}, vminp = {INFINITY, INFINITY};
    float r1 = 0.f, r2 = 0.f;
    int zcc = 0;
    const int nli = (lane + 1) & 63;

#pragma unroll
    for (int k = 0; k < 5; ++k) {
        const float x0 = X[k][0], x1 = X[k][1], x2v = X[k][2], x3 = X[k][3];
        // next-two-elements: lane<63 <- lane+1's chunk k; lane63 <- lane0's
        // chunk k+1 (push-value). k==4: push 0 -> seam products vanish; the
        // half0 seam (x[1279]x[1280]...) is fixed up post-barrier from LDS.
        float v0, v1;
        if (k < 4) { v0 = (lane == 0) ? X[k + 1][0] : x0;
                     v1 = (lane == 0) ? X[k + 1][1] : x1; }
        else       { v0 = (lane == 0) ? 0.f : x0;
                     v1 = (lane == 0) ? 0.f : x1; }
        const float n0 = __shfl(v0, nli);
        const float n1 = __shfl(v1, nli);

        f32x2 lo = __builtin_shufflevector(X[k], X[k], 0, 1);
        f32x2 hi = __builtin_shufflevector(X[k], X[k], 2, 3);
        sp += lo + hi;
        qp = __builtin_elementwise_fma(lo, lo, qp);     // exact-path Σx² partials
        qp = __builtin_elementwise_fma(hi, hi, qp);
        const f32x2 ql = lo * lo, qh = hi * hi;         // raw squares for moments
        c3p = __builtin_elementwise_fma(ql, lo, c3p);   // Σx³
        c3p = __builtin_elementwise_fma(qh, hi, c3p);
        c4p = __builtin_elementwise_fma(ql, ql, c4p);   // Σx⁴
        c4p = __builtin_elementwise_fma(qh, qh, c4p);
        sabsp += __builtin_elementwise_max(lo, -lo);
        sabsp += __builtin_elementwise_max(hi, -hi);
        vmaxp = __builtin_elementwise_max(vmaxp, __builtin_elementwise_max(lo, hi));
        vminp = __builtin_elementwise_min(vminp, __builtin_elementwise_min(lo, hi));

        const unsigned long long m0 = __ballot(x0  < 0.f);
        const unsigned long long m1 = __ballot(x1  < 0.f);
        const unsigned long long m2 = __ballot(x2v < 0.f);
        const unsigned long long m3 = __ballot(x3  < 0.f);
        const unsigned long long mn = __ballot(n0  < 0.f);
        zcc += __popcll(m0 ^ m1) + __popcll(m1 ^ m2) + __popcll(m2 ^ m3);
        zcc += __popcll((m3 ^ mn) & ((k == 4) ? 0x7FFFFFFFFFFFFFFFULL : ~0ULL));

        r1 = fmaf(x0, x1, fmaf(x1, x2v, fmaf(x2v, x3, fmaf(x3, n0, r1))));
        r2 = fmaf(x0, x2v, fmaf(x1, x3, fmaf(x2v, n0, fmaf(x3, n1, r2))));
    }

    const double sum_l = (double)sp.x + (double)sp.y;
    const double sq_l  = (double)qp.x + (double)qp.y;
    const double sum_u = readlane_f64(wave_sum_f64(sum_l), 63);
    const double sq_u  = readlane_f64(wave_sum_f64(sq_l), 63);

    const float sabs_t = wave_sum_f32(sabsp.x + sabsp.y);
    const float c3_t   = wave_sum_f32(c3p.x + c3p.y);
    const float c4_t   = wave_sum_f32(c4p.x + c4p.y);
    const float vmax_t = wave_max_f32(fmaxf(vmaxp.x, vmaxp.y));
    const float vmin_t = wave_min_f32(fminf(vminp.x, vminp.y));

    // exchange sums; half1 publishes x[1280],x[1281] for half0's seam fixups
    if (lane == 0) {
        Lsum[wid] = sum_u;  Lsq[wid] = sq_u;
        if (hidx == 1) { Lnb[rsl][0] = X[0][0]; Lnb[rsl][1] = X[0][1]; }
    }
    __syncthreads();
    const double tsum = Lsum[rsl * 2] + Lsum[rsl * 2 + 1];
    const double tsq  = Lsq[rsl * 2]  + Lsq[rsl * 2 + 1];

    const double mean = tsum * (1.0 / S_LEN);
    const double var  = (tsq - tsum * mean) * (1.0 / (S_LEN - 1));  // n*mean^2 ~1 << tsq
    const double thr  = 3.0 * sqrt(var);
    const double bhi = mean + thr, blo = mean - thr;
    float bhi_f = (float)bhi;
    if ((double)bhi_f > bhi) bhi_f = __int_as_float(__float_as_int(bhi_f) - 1);  // RD (bhi>0)
    float blo_f = (float)blo;
    if ((double)blo_f < blo) blo_f = __int_as_float(__float_as_int(blo_f) - 1);  // RU (blo<0)

    // ---- post-barrier tail: outlier ballots only ----
    int outc = 0;
#pragma unroll
    for (int k = 0; k < 5; ++k) {
        outc += __popcll(__ballot(X[k][0] > bhi_f || X[k][0] < blo_f));
        outc += __popcll(__ballot(X[k][1] > bhi_f || X[k][1] < blo_f));
        outc += __popcll(__ballot(X[k][2] > bhi_f || X[k][2] < blo_f));
        outc += __popcll(__ballot(X[k][3] > bhi_f || X[k][3] < blo_f));
    }

    // seam fixups (half0 only): lag products and zcr bit across x[1279]|x[1280]
    const float nb0 = Lnb[rsl][0], nb1 = Lnb[rsl][1];
    int zcf = zcc;
    if (hidx == 0) {
        const int xe = __builtin_amdgcn_readlane(__float_as_int(X[4][3]), 63);  // x[1279]
        zcf += ((xe ^ __float_as_int(nb0)) < 0) ? 1 : 0;
        if (lane == 63) {
            r1 = fmaf(X[4][3], nb0, r1);
            r2 = fmaf(X[4][2], nb0, fmaf(X[4][3], nb1, r2));
        }
    }
    const float r1_t = wave_sum_f32(r1);
    const float r2_t = wave_sum_f32(r2);

    float ep_a, ep_b;   // half0: x[0],x[1];  half1: x[2558],x[2559]
    if (hidx == 0) {
        ep_a = __int_as_float(__builtin_amdgcn_readlane(__float_as_int(X[0][0]), 0));
        ep_b = __int_as_float(__builtin_amdgcn_readlane(__float_as_int(X[0][1]), 0));
    } else {
        ep_a = X[4][2];  ep_b = X[4][3];   // valid on lane 63 (the storing lane)
    }

    if (lane == 63) {
        double2* Wd = reinterpret_cast<double2*>(ws);
        f32x4*   Wf = reinterpret_cast<f32x4*>(ws);
        double2 dsum; dsum.x = sum_u; dsum.y = sq_u;
        Wd[(size_t)hidx * NROWS + row] = dsum;                       // chunks 0,1
        const size_t b = (size_t)(2 + hidx * 3) * NROWS + row;       // chunks 2..7
        Wf[b]             = f32x4{sabs_t, vmax_t, vmin_t, c3_t};
        Wf[b + NROWS]     = f32x4{c4_t, r1_t, r2_t, (float)outc};
        Wf[b + 2 * NROWS] = f32x4{(float)zcf, ep_a, ep_b, 0.f};
    }
}

__global__ __launch_bounds__(256)
void health_finalize(const float* __restrict__ ws, float* __restrict__ out) {
    const int row = blockIdx.x * 256 + threadIdx.x;
    const double2* Wd = reinterpret_cast<const double2*>(ws);
    const f32x4*   Wf = reinterpret_cast<const f32x4*>(ws);

    const double2 s0 = Wd[row], s1 = Wd[NROWS + row];
    const f32x4 a0 = Wf[2 * NROWS + row], a1 = Wf[3 * NROWS + row], a2 = Wf[4 * NROWS + row];
    const f32x4 b0 = Wf[5 * NROWS + row], b1 = Wf[6 * NROWS + row], b2 = Wf[7 * NROWS + row];

    const double tsum = s0.x + s1.x;
    const double tsq  = s0.y + s1.y;
    const double mean = tsum * (1.0 / S_LEN);
    const double var  = (tsq - tsum * mean) * (1.0 / (S_LEN - 1));
    const double stdv = sqrt(var);

    const float tabs = a0[0] + b0[0];
    const float tmax = fmaxf(a0[1], b0[1]);
    const float tmin = fminf(a0[2], b0[2]);
    const double c3raw = (double)a0[3] + (double)b0[3];   // Σx³
    const double c4raw = (double)a1[0] + (double)b1[0];   // Σx⁴
    const double r1t = (double)a1[1] + (double)b1[1];
    const double r2t = (double)a1[2] + (double)b1[2];
    const float outt = a1[3] + b1[3];
    const float zct  = a2[0] + b2[0];
    const double e0 = (double)a2[1], e1 = (double)a2[2];   // x[0], x[1]
    const double e2 = (double)b2[1], e3 = (double)b2[2];   // x[2558], x[2559]

    // central moments from raw moments (f64 binomial; no cancellation hazard)
    const double n = (double)S_LEN;
    const double mu2 = mean * mean;
    const double s3 = c3raw - 3.0 * mean * tsq + 2.0 * n * mu2 * mean;
    const double s4 = c4raw - 4.0 * mean * c3raw + 6.0 * mu2 * tsq - 3.0 * n * mu2 * mu2;

    const double rms  = sqrt(tsq * (1.0 / S_LEN));
    const double skew = (s3 * (1.0 / S_LEN)) / (var * stdv);
    const double kurt = (s4 * (1.0 / S_LEN)) / (var * var);
    const float  amax = fmaxf(fabsf(tmax), fabsf(tmin));
    const double shape   = rms * (double)S_LEN / (double)tabs;
    const double impulse = (double)amax * (double)S_LEN / (double)tabs;

    // Hjorth via lag-correlation identities (exact over the f32 samples):
    const double Q = tsq;
    const double s1q = 2.0 * Q - 2.0 * r1t - e0 * e0 - e3 * e3;
    const double s2q = 6.0 * Q - 8.0 * r1t + 2.0 * r2t
                     + 4.0 * (e0 * e1 + e2 * e3)
                     - 5.0 * e0 * e0 - e1 * e1 - e2 * e2 - 5.0 * e3 * e3;
    const double sd1 = e3 - e0;
    const double sd2 = (e3 - e2) - (e1 - e0);
    const double var1 = (s1q - sd1 * sd1 * (1.0 / (S_LEN - 1))) * (1.0 / (S_LEN - 2));
    const double var2 = (s2q - sd2 * sd2 * (1.0 / (S_LEN - 2))) * (1.0 / (S_LEN - 3));

    float* o = out + (size_t)row * 15;
    o[0]  = (float)mean;
    o[1]  = tmax;
    o[2]  = tmin;
    o[3]  = tmax - tmin;
    o[4]  = (float)var;
    o[5]  = (float)rms;
    o[6]  = (float)skew;
    o[7]  = (float)kurt;
    o[8]  = (float)shape;
    o[9]  = (float)impulse;
    o[10] = outt;
    o[11] = zct * (1.0f / (2.0f * S_LEN));
    o[12] = (float)var;
    o[13] = (float)sqrt(var1 / var);
    o[14] = (float)sqrt(var2 / var1);
}

extern "C" void kernel_launch(void* const* d_in, const int* in_sizes, int n_in,
                              void* d_out, int out_size, void* d_ws, size_t ws_size,
                              hipStream_t stream) {
    (void)in_sizes; (void)n_in; (void)ws_size; (void)out_size;
    const float* in = (const float*)d_in[0];
    float* out = (float*)d_out;
    float* ws  = (float*)d_ws;
    health_pass1<<<8192, 256, 0, stream>>>(in, ws);
    health_finalize<<<64, 256, 0, stream>>>(ws, out);
}